// Round 7
// baseline (425.137 us; speedup 1.0000x reference)
//
#include <hip/hip_runtime.h>
#include <hip/hip_bf16.h>

typedef __attribute__((ext_vector_type(8))) short short8;
typedef __attribute__((ext_vector_type(4))) short short4v;
typedef __attribute__((ext_vector_type(4))) float f32x4;
typedef __hip_bfloat16 bf16;

#define SEQ 2048
#define DIM 2048
#define NH 32
#define NKV 8
#define HD 64
#define QKVD 3072
#define KVD 512
#define SMSCALE 0.18033688011112042f  /* 0.125 * log2(e), folded into Q at rope time */

__device__ inline void gld_lds16(const bf16* g, bf16* l) {
    __builtin_amdgcn_global_load_lds((const __attribute__((address_space(1))) void*)g,
                                     (__attribute__((address_space(3))) void*)l, 16, 0, 0);
}

__device__ inline void store_val(float* p, float v) { *p = v; }
__device__ inline void store_val(bf16* p, float v) { *p = __float2bfloat16(v); }

__device__ inline unsigned pkbf16(float a, float b) {
    __hip_bfloat162 h = __float22bfloat162_rn(make_float2(a, b));
    return *(unsigned*)&h;
}

__device__ inline float b2f(short x) {
    unsigned u = (unsigned)(unsigned short)x << 16;
    union { unsigned u; float f; } c; c.u = u; return c.f;
}

// ---------------- fused fp32 -> bf16 convert for x | wqkv | wo ----------------
__global__ void cvt3_kernel(const float* __restrict__ x, const float* __restrict__ wqkv,
                            const float* __restrict__ wo, bf16* __restrict__ out) {
    int i = blockIdx.x * blockDim.x + threadIdx.x;
    const float* src; int off;
    if (i < 2097152) { src = x; off = i; }
    else if (i < 3670016) { src = wqkv; off = i - 2097152; }
    else { src = wo; off = i - 3670016; }
    float4 v = ((const float4*)src)[off];
    uint2 u;
    u.x = pkbf16(v.x, v.y);
    u.y = pkbf16(v.z, v.w);
    ((uint2*)out)[i] = u;
}

// ---------------- NT GEMM: C[M,N] = A[M,K] * Bt[N,K]^T  (m97 structure, verified) ----------------
template <typename CT>
__global__ __launch_bounds__(256, 3) void gemm_nt(const bf16* __restrict__ A,
                                                  const bf16* __restrict__ Bt,
                                                  CT* __restrict__ C,
                                                  int M, int N, int K) {
    __shared__ bf16 As[128 * 32];
    __shared__ bf16 Bs[128 * 32];
    const int tid = threadIdx.x;
    const int lane = tid & 63;
    const int quad = lane >> 4;
    const int r16 = lane & 15;
    const int wave = tid >> 6;
    const int bm = blockIdx.y * 128;
    const int bn = blockIdx.x * 128;
    const int wm = (wave >> 1) * 64;
    const int wn = (wave & 1) * 64;

    f32x4 acc[4][4] = {};

    const int arow = tid >> 2;
    const int kch = (tid & 3) * 8;
    const bf16* Ap = A + (size_t)(bm + arow) * K + kch;
    const bf16* Bp = Bt + (size_t)(bn + arow) * K + kch;
    bf16* Asd = As + tid * 8;
    bf16* Bsd = Bs + tid * 8;
    const int kq = quad * 8;

    for (int k0 = 0; k0 < K; k0 += 32) {
        __syncthreads();
        gld_lds16(Ap, Asd);
        gld_lds16(Ap + (size_t)64 * K, Asd + 64 * 32);
        gld_lds16(Bp, Bsd);
        gld_lds16(Bp + (size_t)64 * K, Bsd + 64 * 32);
        Ap += 32; Bp += 32;
        __syncthreads();
        short8 af[4], bfr[4];
#pragma unroll
        for (int i = 0; i < 4; i++)
            af[i] = *(const short8*)(As + (wm + i * 16 + r16) * 32 + kq);
#pragma unroll
        for (int j = 0; j < 4; j++)
            bfr[j] = *(const short8*)(Bs + (wn + j * 16 + r16) * 32 + kq);
#pragma unroll
        for (int i = 0; i < 4; i++)
#pragma unroll
            for (int j = 0; j < 4; j++)
                acc[i][j] = __builtin_amdgcn_mfma_f32_16x16x32_bf16(af[i], bfr[j], acc[i][j], 0, 0, 0);
    }
#pragma unroll
    for (int i = 0; i < 4; i++)
#pragma unroll
        for (int j = 0; j < 4; j++) {
            int row = bm + wm + i * 16 + quad * 4;
            int col = bn + wn + j * 16 + r16;
#pragma unroll
            for (int r = 0; r < 4; r++)
                store_val(C + (size_t)(row + r) * N + col, acc[i][j][r]);
        }
}

// ---------------- RoPE on Q,K, vectorized x8 (Q pre-scaled by SMSCALE) ----------------
__global__ void rope_qk_kernel(const bf16* __restrict__ qkv, const float* __restrict__ fc,
                               bf16* __restrict__ qr, bf16* __restrict__ kr) {
    const int row = blockIdx.y;
    const int s = row & (SEQ - 1);
    const int col = (blockIdx.x * 64 + threadIdx.x) * 8;  // 0..2552, step 8
    const bf16* src = qkv + (size_t)row * QKVD + col;
    short8 v = *(const short8*)src;
    const int j0 = (col & 63) >> 1;
    const float4* fcp = (const float4*)(fc + ((size_t)s * 32 + j0) * 2);
    float4 f01 = fcp[0];
    float4 f23 = fcp[1];

    bf16* dst;
    float sc;
    if (col < DIM) { dst = qr + (size_t)row * DIM + col; sc = SMSCALE; }
    else           { dst = kr + (size_t)row * KVD + (col - DIM); sc = 1.0f; }

    float x0 = b2f(v[0]), x1 = b2f(v[1]), x2 = b2f(v[2]), x3 = b2f(v[3]);
    float x4 = b2f(v[4]), x5 = b2f(v[5]), x6 = b2f(v[6]), x7 = b2f(v[7]);
    float c0 = f01.x * sc, s0 = f01.y * sc, c1 = f01.z * sc, s1 = f01.w * sc;
    float c2 = f23.x * sc, s2 = f23.y * sc, c3 = f23.z * sc, s3 = f23.w * sc;

    uint4 o;
    o.x = pkbf16(x0 * c0 - x1 * s0, x1 * c0 + x0 * s0);
    o.y = pkbf16(x2 * c1 - x3 * s1, x3 * c1 + x2 * s1);
    o.z = pkbf16(x4 * c2 - x5 * s2, x5 * c2 + x4 * s2);
    o.w = pkbf16(x6 * c3 - x7 * s3, x7 * c3 + x6 * s3);
    *(uint4*)dst = o;
}

// ---------------- V transpose: qkv[s][2560+kvh*64+d] -> vt[(b,kvh,d)][s] ----------------
__global__ void rope_v_kernel(const bf16* __restrict__ qkv, bf16* __restrict__ vt) {
    const int t = threadIdx.x;
    const int so = t & 63;
    const int dq = t >> 6;
    const int bk = blockIdx.y;
    const int s = blockIdx.x * 64 + so;
    const int b = bk >> 3;
    const bf16* src = qkv + ((size_t)b * SEQ + s) * QKVD + DIM + KVD + (bk & 7) * HD + dq * 16;
    short8 v0 = *(const short8*)src;
    short8 v1 = *(const short8*)(src + 8);
    short* dst = (short*)(vt + ((size_t)bk * HD + dq * 16) * SEQ + s);
#pragma unroll
    for (int j = 0; j < 8; j++) dst[(size_t)j * SEQ] = v0[j];
#pragma unroll
    for (int j = 0; j < 8; j++) dst[(size_t)(8 + j) * SEQ] = v1[j];
}

// ---------------- Flash attention: NO LDS, no barriers -- direct global->register fragments ----------------
// K/V per (b,kvh) = 256 KB each, L2-resident (FETCH-verified) and XCD-pinned by the
// grid swizzle; each 8 KB tile is fully consumed, and 4 waves (heads) + 2 blocks/CU
// share tiles through L1 (32 KB). So LDS staging was pure overhead (catalog m169):
// fragments now load straight from global:
//   K  (QK^T A-op, 16x16x32): lane(quad,r16) reads 16B at kr[key=kbase+n*16+r16][d=quad*8..+7]
//   V^T (PV  A-op, 16x16x16): lane reads 8B at vt[d=dt*16+r16][s=kbase+n*16+quad*4..+3]
// (address math derived from -- and equal to -- the previous LDS fragment layouts).
// This deletes every __syncthreads, every vmcnt(0) drain, and all bank conflicts;
// waves run fully independently. kf loads issue before vf (vmcnt FIFO: QK^T's wait
// leaves vf in flight; PV's wait covered by exp phase). Two 16-row sub-tiles per
// 64-key pass amortize kf/vf register loads (each feeds 4 MFMAs).
__global__ __launch_bounds__(256, 2) void attn_kernel(const bf16* __restrict__ qr,
                                                      const bf16* __restrict__ kr,
                                                      const bf16* __restrict__ vt,
                                                      bf16* __restrict__ out) {
    const int t = threadIdx.x;
    const int lane = t & 63;
    const int wv = t >> 6;
    const int quad = lane >> 4;
    const int r16 = lane & 15;

    const int wg = blockIdx.x;          // 0..511
    const int xcd = wg & 7;
    const int kk = wg >> 3;             // 0..63
    const int bk = xcd * 2 + (kk & 1);  // b*8+kvh: 2 kv-groups per XCD (L2-resident)
    const int pairIdx = kk >> 1;        // 0..31
    const int b = bk >> 3;
    const int kvh = bk & 7;
    const int h = kvh * 4 + wv;

    // per-lane direct fragment base pointers
    const bf16* Kgd = kr + ((size_t)b * SEQ + r16) * KVD + kvh * HD + quad * 8;
    const bf16* Vgd = vt + ((size_t)(b * NKV + kvh) * HD + r16) * SEQ + quad * 4;

    union PB { short4v s; unsigned u[2]; };
    const short one_bf16 = (short)0x3F80;
    const short4v ones = {one_bf16, one_bf16, one_bf16, one_bf16};

#pragma unroll 1
    for (int seg = 0; seg < 2; seg++) {
        const int qt = seg ? (63 - pairIdx) : pairIdx;   // 32-row tile index
        const int q0 = qt * 32;
        const int nkb = (qt >> 1) + 1;

        // Q fragments for both 16-row sub-tiles (B-operand), pre-scaled by SMSCALE
        const bf16* QpA = qr + ((size_t)b * SEQ + q0 + r16) * DIM + h * HD + quad * 8;
        const bf16* QpB = QpA + (size_t)16 * DIM;
        short8 qaA0 = *(const short8*)(QpA);
        short8 qaA1 = *(const short8*)(QpA + 32);
        short8 qaB0 = *(const short8*)(QpB);
        short8 qaB1 = *(const short8*)(QpB + 32);

        f32x4 oA[4] = {}, oB[4] = {};
        f32x4 olA = {}, olB = {};

#pragma unroll 1
        for (int kb = 0; kb < nkb; kb++) {
            const int kbase = kb * 64;

            // K fragments first (vmcnt FIFO: QK^T's wait leaves vf outstanding)
            short8 kfr[4][2];
            const bf16* Kp = Kgd + (size_t)kbase * KVD;
#pragma unroll
            for (int n = 0; n < 4; n++) {
                kfr[n][0] = *(const short8*)(Kp + (size_t)(n * 16) * KVD);
                kfr[n][1] = *(const short8*)(Kp + (size_t)(n * 16) * KVD + 32);
            }
            // V fragments issued now; consumed after the exp phase
            short4v vf[4][4];
#pragma unroll
            for (int dt = 0; dt < 4; dt++) {
                const bf16* Vp = Vgd + (size_t)(dt * 16) * SEQ + kbase;
#pragma unroll
                for (int n = 0; n < 4; n++)
                    vf[dt][n] = *(const short4v*)(Vp + n * 16);
            }
            __builtin_amdgcn_sched_barrier(0);

            // S^T = K * Q^T for both sub-tiles; kf registers feed 4 MFMAs each
            const f32x4 z = {0.f, 0.f, 0.f, 0.f};
            f32x4 stA[4], stB[4];
            __builtin_amdgcn_s_setprio(1);
#pragma unroll
            for (int n = 0; n < 4; n++) {
                stA[n] = __builtin_amdgcn_mfma_f32_16x16x32_bf16(kfr[n][0], qaA0, z, 0, 0, 0);
                stA[n] = __builtin_amdgcn_mfma_f32_16x16x32_bf16(kfr[n][1], qaA1, stA[n], 0, 0, 0);
                stB[n] = __builtin_amdgcn_mfma_f32_16x16x32_bf16(kfr[n][0], qaB0, z, 0, 0, 0);
                stB[n] = __builtin_amdgcn_mfma_f32_16x16x32_bf16(kfr[n][1], qaB1, stB[n], 0, 0, 0);
            }
            __builtin_amdgcn_s_setprio(0);

            if (kb == nkb - 1) {  // diagonal block: causal mask in place
#pragma unroll
                for (int n = 0; n < 4; n++)
#pragma unroll
                    for (int r = 0; r < 4; r++) {
                        int key = kbase + n * 16 + quad * 4 + r;
                        if (key > q0 + r16) stA[n][r] = -__builtin_inff();
                        if (key > q0 + 16 + r16) stB[n][r] = -__builtin_inff();
                    }
            }

            // p = exp2(s) (no max, no rescale; masked keys -> 0)
            PB pbsA[4], pbsB[4];
#pragma unroll
            for (int n = 0; n < 4; n++) {
                float a0 = exp2f(stA[n][0]), a1 = exp2f(stA[n][1]);
                float a2 = exp2f(stA[n][2]), a3 = exp2f(stA[n][3]);
                pbsA[n].u[0] = pkbf16(a0, a1);
                pbsA[n].u[1] = pkbf16(a2, a3);
                float b0 = exp2f(stB[n][0]), b1 = exp2f(stB[n][1]);
                float b2 = exp2f(stB[n][2]), b3 = exp2f(stB[n][3]);
                pbsB[n].u[0] = pkbf16(b0, b1);
                pbsB[n].u[1] = pkbf16(b2, b3);
            }

            // O^T += V^T * P^T (both tiles); denominators via ones-MFMA
            __builtin_amdgcn_s_setprio(1);
#pragma unroll
            for (int dt = 0; dt < 4; dt++)
#pragma unroll
                for (int n = 0; n < 4; n++) {
                    oA[dt] = __builtin_amdgcn_mfma_f32_16x16x16bf16_1k(vf[dt][n], pbsA[n].s, oA[dt], 0, 0, 0);
                    oB[dt] = __builtin_amdgcn_mfma_f32_16x16x16bf16_1k(vf[dt][n], pbsB[n].s, oB[dt], 0, 0, 0);
                }
#pragma unroll
            for (int n = 0; n < 4; n++) {
                olA = __builtin_amdgcn_mfma_f32_16x16x16bf16_1k(ones, pbsA[n].s, olA, 0, 0, 0);
                olB = __builtin_amdgcn_mfma_f32_16x16x16bf16_1k(ones, pbsB[n].s, olB, 0, 0, 0);
            }
            __builtin_amdgcn_s_setprio(0);
        }

        // epilogue: ol[r] identical across r and quads -> no reduction needed
        float invA = 1.f / olA[0];
        float invB = 1.f / olB[0];
        bf16* OpA = out + ((size_t)b * SEQ + q0 + r16) * DIM + h * HD + quad * 4;
        bf16* OpB = OpA + (size_t)16 * DIM;
#pragma unroll
        for (int dt = 0; dt < 4; dt++) {
            PB pka, pkb;
            pka.u[0] = pkbf16(oA[dt][0] * invA, oA[dt][1] * invA);
            pka.u[1] = pkbf16(oA[dt][2] * invA, oA[dt][3] * invA);
            *(short4v*)(OpA + dt * 16) = pka.s;
            pkb.u[0] = pkbf16(oB[dt][0] * invB, oB[dt][1] * invB);
            pkb.u[1] = pkbf16(oB[dt][2] * invB, oB[dt][3] * invB);
            *(short4v*)(OpB + dt * 16) = pkb.s;
        }
    }
}

extern "C" void kernel_launch(void* const* d_in, const int* in_sizes, int n_in,
                              void* d_out, int out_size, void* d_ws, size_t ws_size,
                              hipStream_t stream) {
    (void)in_sizes; (void)n_in; (void)out_size; (void)ws_size;
    const float* x    = (const float*)d_in[0];
    const float* fc   = (const float*)d_in[1];
    const float* wqkv = (const float*)d_in[3];
    const float* wo   = (const float*)d_in[4];
    float* out = (float*)d_out;

    char* w = (char*)d_ws;
    bf16* xb    = (bf16*)(w);
    bf16* wqkvb = (bf16*)(w + 16777216);
    bf16* wob   = (bf16*)(w + 29360128);
    bf16* qkvb  = (bf16*)(w + 37748736);
    bf16* kr    = (bf16*)(w + 62914560);
    bf16* vt    = (bf16*)(w + 67108864);
    bf16* qr = xb;
    bf16* attnb = qkvb;

    cvt3_kernel<<<18432, 256, 0, stream>>>(x, wqkv, wo, xb);
    gemm_nt<bf16><<<dim3(24, 32), 256, 0, stream>>>(xb, wqkvb, qkvb, 4096, QKVD, DIM);
    rope_qk_kernel<<<dim3(5, 4096), 64, 0, stream>>>(qkvb, fc, qr, kr);
    rope_v_kernel<<<dim3(32, 16), 256, 0, stream>>>(qkvb, vt);
    attn_kernel<<<dim3(512), 256, 0, stream>>>(qr, kr, vt, attnb);
    gemm_nt<float><<<dim3(16, 32), 256, 0, stream>>>(attnb, wob, out, 4096, DIM, DIM);
}

// Round 9
// 322.380 us; speedup vs baseline: 1.3187x; 1.3187x over previous
//
#include <hip/hip_runtime.h>
#include <hip/hip_bf16.h>

typedef __attribute__((ext_vector_type(8))) short short8;
typedef __attribute__((ext_vector_type(4))) short short4v;
typedef __attribute__((ext_vector_type(4))) float f32x4;
typedef __hip_bfloat16 bf16;

#define SEQ 2048
#define DIM 2048
#define NH 32
#define NKV 8
#define HD 64
#define QKVD 3072
#define KVD 512
#define SMSCALE 0.18033688011112042f  /* 0.125 * log2(e), folded into Q at rope time */

__device__ inline void gld_lds16(const bf16* g, bf16* l) {
    __builtin_amdgcn_global_load_lds((const __attribute__((address_space(1))) void*)g,
                                     (__attribute__((address_space(3))) void*)l, 16, 0, 0);
}

__device__ inline void store_val(float* p, float v) { *p = v; }
__device__ inline void store_val(bf16* p, float v) { *p = __float2bfloat16(v); }

__device__ inline unsigned pkbf16(float a, float b) {
    __hip_bfloat162 h = __float22bfloat162_rn(make_float2(a, b));
    return *(unsigned*)&h;
}

__device__ inline float b2f(short x) {
    unsigned u = (unsigned)(unsigned short)x << 16;
    union { unsigned u; float f; } c; c.u = u; return c.f;
}

// ---------------- fused fp32 -> bf16 convert for x | wqkv | wo ----------------
__global__ void cvt3_kernel(const float* __restrict__ x, const float* __restrict__ wqkv,
                            const float* __restrict__ wo, bf16* __restrict__ out) {
    int i = blockIdx.x * blockDim.x + threadIdx.x;
    const float* src; int off;
    if (i < 2097152) { src = x; off = i; }
    else if (i < 3670016) { src = wqkv; off = i - 2097152; }
    else { src = wo; off = i - 3670016; }
    float4 v = ((const float4*)src)[off];
    uint2 u;
    u.x = pkbf16(v.x, v.y);
    u.y = pkbf16(v.z, v.w);
    ((uint2*)out)[i] = u;
}

// ---------------- NT GEMM: C[M,N] = A[M,K] * Bt[N,K]^T  (m97 structure, verified) ----------------
template <typename CT>
__global__ __launch_bounds__(256, 3) void gemm_nt(const bf16* __restrict__ A,
                                                  const bf16* __restrict__ Bt,
                                                  CT* __restrict__ C,
                                                  int M, int N, int K) {
    __shared__ bf16 As[128 * 32];
    __shared__ bf16 Bs[128 * 32];
    const int tid = threadIdx.x;
    const int lane = tid & 63;
    const int quad = lane >> 4;
    const int r16 = lane & 15;
    const int wave = tid >> 6;
    const int bm = blockIdx.y * 128;
    const int bn = blockIdx.x * 128;
    const int wm = (wave >> 1) * 64;
    const int wn = (wave & 1) * 64;

    f32x4 acc[4][4] = {};

    const int arow = tid >> 2;
    const int kch = (tid & 3) * 8;
    const bf16* Ap = A + (size_t)(bm + arow) * K + kch;
    const bf16* Bp = Bt + (size_t)(bn + arow) * K + kch;
    bf16* Asd = As + tid * 8;
    bf16* Bsd = Bs + tid * 8;
    const int kq = quad * 8;

    for (int k0 = 0; k0 < K; k0 += 32) {
        __syncthreads();
        gld_lds16(Ap, Asd);
        gld_lds16(Ap + (size_t)64 * K, Asd + 64 * 32);
        gld_lds16(Bp, Bsd);
        gld_lds16(Bp + (size_t)64 * K, Bsd + 64 * 32);
        Ap += 32; Bp += 32;
        __syncthreads();
        short8 af[4], bfr[4];
#pragma unroll
        for (int i = 0; i < 4; i++)
            af[i] = *(const short8*)(As + (wm + i * 16 + r16) * 32 + kq);
#pragma unroll
        for (int j = 0; j < 4; j++)
            bfr[j] = *(const short8*)(Bs + (wn + j * 16 + r16) * 32 + kq);
#pragma unroll
        for (int i = 0; i < 4; i++)
#pragma unroll
            for (int j = 0; j < 4; j++)
                acc[i][j] = __builtin_amdgcn_mfma_f32_16x16x32_bf16(af[i], bfr[j], acc[i][j], 0, 0, 0);
    }
#pragma unroll
    for (int i = 0; i < 4; i++)
#pragma unroll
        for (int j = 0; j < 4; j++) {
            int row = bm + wm + i * 16 + quad * 4;
            int col = bn + wn + j * 16 + r16;
#pragma unroll
            for (int r = 0; r < 4; r++)
                store_val(C + (size_t)(row + r) * N + col, acc[i][j][r]);
        }
}

// ---------------- RoPE on Q,K, vectorized x8 (Q pre-scaled by SMSCALE) ----------------
__global__ void rope_qk_kernel(const bf16* __restrict__ qkv, const float* __restrict__ fc,
                               bf16* __restrict__ qr, bf16* __restrict__ kr) {
    const int row = blockIdx.y;
    const int s = row & (SEQ - 1);
    const int col = (blockIdx.x * 64 + threadIdx.x) * 8;  // 0..2552, step 8
    const bf16* src = qkv + (size_t)row * QKVD + col;
    short8 v = *(const short8*)src;
    const int j0 = (col & 63) >> 1;
    const float4* fcp = (const float4*)(fc + ((size_t)s * 32 + j0) * 2);
    float4 f01 = fcp[0];
    float4 f23 = fcp[1];

    bf16* dst;
    float sc;
    if (col < DIM) { dst = qr + (size_t)row * DIM + col; sc = SMSCALE; }
    else           { dst = kr + (size_t)row * KVD + (col - DIM); sc = 1.0f; }

    float x0 = b2f(v[0]), x1 = b2f(v[1]), x2 = b2f(v[2]), x3 = b2f(v[3]);
    float x4 = b2f(v[4]), x5 = b2f(v[5]), x6 = b2f(v[6]), x7 = b2f(v[7]);
    float c0 = f01.x * sc, s0 = f01.y * sc, c1 = f01.z * sc, s1 = f01.w * sc;
    float c2 = f23.x * sc, s2 = f23.y * sc, c3 = f23.z * sc, s3 = f23.w * sc;

    uint4 o;
    o.x = pkbf16(x0 * c0 - x1 * s0, x1 * c0 + x0 * s0);
    o.y = pkbf16(x2 * c1 - x3 * s1, x3 * c1 + x2 * s1);
    o.z = pkbf16(x4 * c2 - x5 * s2, x5 * c2 + x4 * s2);
    o.w = pkbf16(x6 * c3 - x7 * s3, x7 * c3 + x6 * s3);
    *(uint4*)dst = o;
}

// ---------------- V transpose: qkv[s][2560+kvh*64+d] -> vt[(b,kvh,d)][s] ----------------
__global__ void rope_v_kernel(const bf16* __restrict__ qkv, bf16* __restrict__ vt) {
    const int t = threadIdx.x;
    const int so = t & 63;
    const int dq = t >> 6;
    const int bk = blockIdx.y;
    const int s = blockIdx.x * 64 + so;
    const int b = bk >> 3;
    const bf16* src = qkv + ((size_t)b * SEQ + s) * QKVD + DIM + KVD + (bk & 7) * HD + dq * 16;
    short8 v0 = *(const short8*)src;
    short8 v1 = *(const short8*)(src + 8);
    short* dst = (short*)(vt + ((size_t)bk * HD + dq * 16) * SEQ + s);
#pragma unroll
    for (int j = 0; j < 8; j++) dst[(size_t)j * SEQ] = v0[j];
#pragma unroll
    for (int j = 0; j < 8; j++) dst[(size_t)(8 + j) * SEQ] = v1[j];
}

// ---------------- Flash attention: 3-buffer LDS, counted vmcnt (T4), no drains ----------------
// R6 measured 3234 cyc/block-iter vs ~600 cyc of compute: the stall was the two
// __syncthreads() per iter (each = s_waitcnt vmcnt(0)); dbuf-2 waits for its own
// just-issued prefetch every iter. Fix: 3 LDS buffers (48 KB), stage TWO tiles
// ahead, raw s_barrier + counted vmcnt(4) -- never drains in the main loop.
//   iter kb: vmcnt(4) [forces stage(kb), issued 2 iters ago; leaves stage(kb+1)
//            in flight]; s_barrier (DMA visible); stage kb+2 -> buf (kb+2)%3
//            (safe: last read at kb-1, ordered by this barrier); compute buf kb%3.
// SEG-BOUNDARY FIX (R8 audit): per segment, one vmcnt(0) after the Q-load issue
// and BEFORE the prologue STAGEs -- drains prior-seg epilogue stores + Q loads so
// the in-loop FIFO is exactly {stage(kb), stage(kb+1)} and vmcnt(4) forces
// precisely stage(kb). Without it, seg>=1's first iter could read unstaged LDS
// (stores+Q polluted the count). 2 drains/block, outside the hot loop.
__global__ __launch_bounds__(256, 2) void attn_kernel(const bf16* __restrict__ qr,
                                                      const bf16* __restrict__ kr,
                                                      const bf16* __restrict__ vt,
                                                      bf16* __restrict__ out) {
    __shared__ bf16 Ks[3 * 4096];  // [buf 3][dchunk 8][key 64][8]  (8 KB / buf)
    __shared__ bf16 Vs[3 * 4096];  // [buf 3][kchunk 8][d 64][8]
    const int t = threadIdx.x;
    const int lane = t & 63;
    const int wv = t >> 6;
    const int quad = lane >> 4;
    const int r16 = lane & 15;

    const int wg = blockIdx.x;          // 0..511
    const int xcd = wg & 7;
    const int kk = wg >> 3;             // 0..63
    const int bk = xcd * 2 + (kk & 1);  // b*8+kvh: 2 kv-groups per XCD (L2-resident)
    const int pairIdx = kk >> 1;        // 0..31
    const int b = bk >> 3;
    const int kvh = bk & 7;
    const int h = kvh * 4 + wv;

    const bf16* Kg = kr + ((size_t)b * SEQ + lane) * KVD + kvh * HD + wv * 8;
    const bf16* Vg = vt + ((size_t)(b * NKV + kvh) * HD + lane) * SEQ + wv * 8;

    const char* kl = (const char*)Ks + quad * 1024 + r16 * 16;
    const char* vl = (const char*)Vs + (quad >> 1) * 1024 + r16 * 16 + (quad & 1) * 8;

    union PB { short4v s; unsigned u[2]; };
    const short one_bf16 = (short)0x3F80;
    const short4v ones = {one_bf16, one_bf16, one_bf16, one_bf16};

#define STAGE(tile, sbuf) {                                        \
        const bf16* Kgn = Kg + (size_t)(tile) * 64 * KVD;          \
        const bf16* Vgn = Vg + (tile) * 64;                        \
        bf16* Ksd = Ks + (sbuf) * 4096 + t * 8;                    \
        bf16* Vsd = Vs + (sbuf) * 4096 + t * 8;                    \
        gld_lds16(Kgn, Ksd);  gld_lds16(Kgn + 32, Ksd + 2048);     \
        gld_lds16(Vgn, Vsd);  gld_lds16(Vgn + 32, Vsd + 2048); }

#pragma unroll 1
    for (int seg = 0; seg < 2; seg++) {
        const int qt = seg ? (63 - pairIdx) : pairIdx;   // 32-row tile index
        const int q0 = qt * 32;
        const int nkb = (qt >> 1) + 1;

        // Q fragments for both 16-row sub-tiles (B-operand), pre-scaled by SMSCALE
        const bf16* QpA = qr + ((size_t)b * SEQ + q0 + r16) * DIM + h * HD + quad * 8;
        const bf16* QpB = QpA + (size_t)16 * DIM;
        short8 qaA0 = *(const short8*)(QpA);
        short8 qaA1 = *(const short8*)(QpA + 32);
        short8 qaB0 = *(const short8*)(QpB);
        short8 qaB1 = *(const short8*)(QpB + 32);
        __builtin_amdgcn_sched_barrier(0);

        // drain prior-seg epilogue stores + these Q loads BEFORE any staging:
        // keeps the in-loop vmcnt FIFO exactly {stage(kb), stage(kb+1)}
        asm volatile("s_waitcnt vmcnt(0)" ::: "memory");

        f32x4 oA[4] = {}, oB[4] = {};
        f32x4 olA = {}, olB = {};

        // seg barrier: all waves' reads of previous segment's buffers complete
        __builtin_amdgcn_s_barrier();
        __builtin_amdgcn_sched_barrier(0);

        // prologue: stage tiles 0 and 1 (into bufs 0,1)
        STAGE(0, 0);
        if (nkb > 1) STAGE(1, 1);

        int cb = 0;   // compute buffer  = kb % 3
        int sb = 2;   // stage target    = (kb+2) % 3

#pragma unroll 1
        for (int kb = 0; kb < nkb; kb++) {
            // counted wait: forces stage(kb); leaves stage(kb+1) in flight
            if (kb == nkb - 1) { asm volatile("s_waitcnt vmcnt(0)" ::: "memory"); }
            else               { asm volatile("s_waitcnt vmcnt(4)" ::: "memory"); }
            __builtin_amdgcn_sched_barrier(0);
            __builtin_amdgcn_s_barrier();
            __builtin_amdgcn_sched_barrier(0);

            if (kb + 2 < nkb) STAGE(kb + 2, sb);

            const char* klb = kl + cb * 8192;
            const char* vlb = vl + cb * 8192;
            const int kbase = kb * 64;

            // S^T = K * Q^T for both sub-tiles; kf fragments read once, used twice
            const f32x4 z = {0.f, 0.f, 0.f, 0.f};
            f32x4 stA[4], stB[4];
            __builtin_amdgcn_s_setprio(1);
#pragma unroll
            for (int n = 0; n < 4; n++) {
                short8 kf0 = *(const short8*)(klb + n * 256);
                short8 kf1 = *(const short8*)(klb + 4096 + n * 256);
                stA[n] = __builtin_amdgcn_mfma_f32_16x16x32_bf16(kf0, qaA0, z, 0, 0, 0);
                stA[n] = __builtin_amdgcn_mfma_f32_16x16x32_bf16(kf1, qaA1, stA[n], 0, 0, 0);
                stB[n] = __builtin_amdgcn_mfma_f32_16x16x32_bf16(kf0, qaB0, z, 0, 0, 0);
                stB[n] = __builtin_amdgcn_mfma_f32_16x16x32_bf16(kf1, qaB1, stB[n], 0, 0, 0);
            }
            __builtin_amdgcn_s_setprio(0);

            // V fragments: read once, shared by both sub-tiles' PV
            short4v vf[4][4];
#pragma unroll
            for (int dt = 0; dt < 4; dt++)
#pragma unroll
                for (int n = 0; n < 4; n++)
                    vf[dt][n] = *(const short4v*)(vlb + n * 2048 + dt * 256);
            __builtin_amdgcn_sched_barrier(0);

            if (kb == nkb - 1) {  // diagonal block: causal mask in place
#pragma unroll
                for (int n = 0; n < 4; n++)
#pragma unroll
                    for (int r = 0; r < 4; r++) {
                        int key = kbase + n * 16 + quad * 4 + r;
                        if (key > q0 + r16) stA[n][r] = -__builtin_inff();
                        if (key > q0 + 16 + r16) stB[n][r] = -__builtin_inff();
                    }
            }

            // p = exp2(s) (no max, no rescale; masked keys -> 0)
            PB pbsA[4], pbsB[4];
#pragma unroll
            for (int n = 0; n < 4; n++) {
                float a0 = exp2f(stA[n][0]), a1 = exp2f(stA[n][1]);
                float a2 = exp2f(stA[n][2]), a3 = exp2f(stA[n][3]);
                pbsA[n].u[0] = pkbf16(a0, a1);
                pbsA[n].u[1] = pkbf16(a2, a3);
                float b0 = exp2f(stB[n][0]), b1 = exp2f(stB[n][1]);
                float b2 = exp2f(stB[n][2]), b3 = exp2f(stB[n][3]);
                pbsB[n].u[0] = pkbf16(b0, b1);
                pbsB[n].u[1] = pkbf16(b2, b3);
            }

            // O^T += V^T * P^T (both tiles); denominators via ones-MFMA
            __builtin_amdgcn_s_setprio(1);
#pragma unroll
            for (int dt = 0; dt < 4; dt++)
#pragma unroll
                for (int n = 0; n < 4; n++) {
                    oA[dt] = __builtin_amdgcn_mfma_f32_16x16x16bf16_1k(vf[dt][n], pbsA[n].s, oA[dt], 0, 0, 0);
                    oB[dt] = __builtin_amdgcn_mfma_f32_16x16x16bf16_1k(vf[dt][n], pbsB[n].s, oB[dt], 0, 0, 0);
                }
#pragma unroll
            for (int n = 0; n < 4; n++) {
                olA = __builtin_amdgcn_mfma_f32_16x16x16bf16_1k(ones, pbsA[n].s, olA, 0, 0, 0);
                olB = __builtin_amdgcn_mfma_f32_16x16x16bf16_1k(ones, pbsB[n].s, olB, 0, 0, 0);
            }
            __builtin_amdgcn_s_setprio(0);

            cb = (cb == 2) ? 0 : cb + 1;
            sb = (sb == 2) ? 0 : sb + 1;
        }

        // epilogue: ol[r] identical across r and quads -> no reduction needed
        float invA = 1.f / olA[0];
        float invB = 1.f / olB[0];
        bf16* OpA = out + ((size_t)b * SEQ + q0 + r16) * DIM + h * HD + quad * 4;
        bf16* OpB = OpA + (size_t)16 * DIM;
#pragma unroll
        for (int dt = 0; dt < 4; dt++) {
            PB pka, pkb;
            pka.u[0] = pkbf16(oA[dt][0] * invA, oA[dt][1] * invA);
            pka.u[1] = pkbf16(oA[dt][2] * invA, oA[dt][3] * invA);
            *(short4v*)(OpA + dt * 16) = pka.s;
            pkb.u[0] = pkbf16(oB[dt][0] * invB, oB[dt][1] * invB);
            pkb.u[1] = pkbf16(oB[dt][2] * invB, oB[dt][3] * invB);
            *(short4v*)(OpB + dt * 16) = pkb.s;
        }
    }
#undef STAGE
}

extern "C" void kernel_launch(void* const* d_in, const int* in_sizes, int n_in,
                              void* d_out, int out_size, void* d_ws, size_t ws_size,
                              hipStream_t stream) {
    (void)in_sizes; (void)n_in; (void)out_size; (void)ws_size;
    const float* x    = (const float*)d_in[0];
    const float* fc   = (const float*)d_in[1];
    const float* wqkv = (const float*)d_in[3];
    const float* wo   = (const float*)d_in[4];
    float* out = (float*)d_out;

    char* w = (char*)d_ws;
    bf16* xb    = (bf16*)(w);
    bf16* wqkvb = (bf16*)(w + 16777216);
    bf16* wob   = (bf16*)(w + 29360128);
    bf16* qkvb  = (bf16*)(w + 37748736);
    bf16* kr    = (bf16*)(w + 62914560);
    bf16* vt    = (bf16*)(w + 67108864);
    bf16* qr = xb;
    bf16* attnb = qkvb;

    cvt3_kernel<<<18432, 256, 0, stream>>>(x, wqkv, wo, xb);
    gemm_nt<bf16><<<dim3(24, 32), 256, 0, stream>>>(xb, wqkvb, qkvb, 4096, QKVD, DIM);
    rope_qk_kernel<<<dim3(5, 4096), 64, 0, stream>>>(qkvb, fc, qr, kr);
    rope_v_kernel<<<dim3(32, 16), 256, 0, stream>>>(qkvb, vt);
    attn_kernel<<<dim3(512), 256, 0, stream>>>(qr, kr, vt, attnb);
    gemm_nt<float><<<dim3(16, 32), 256, 0, stream>>>(attnb, wob, out, 4096, DIM, DIM);
}